// Round 1
// baseline (440.665 us; speedup 1.0000x reference)
//
#include <hip/hip_runtime.h>

typedef __attribute__((ext_vector_type(8))) short s16x8;
typedef __attribute__((ext_vector_type(4))) float f32x4;

static __device__ __forceinline__ unsigned short f2bf(float f) {
  union { float f; unsigned int u; } v; v.f = f;
  unsigned int u = v.u;
  u += 0x7fffu + ((u >> 16) & 1u);
  return (unsigned short)(u >> 16);
}

// ---------------------------------------------------------------- cast weights
__global__ __launch_bounds__(256) void cast_w(const float* __restrict__ in,
                                              unsigned short* __restrict__ out, int n) {
  int i = (blockIdx.x * 256 + threadIdx.x) * 4;
  if (i >= n) return;
  float4 f = *reinterpret_cast<const float4*>(in + i);
  ushort4 o;
  o.x = f2bf(f.x); o.y = f2bf(f.y); o.z = f2bf(f.z); o.w = f2bf(f.w);
  *reinterpret_cast<ushort4*>(out + i) = o;
}

// ---------------------------------------------------------------- GEMM: C = A(f32) @ W(bf16)^T
// A: M x K fp32 row-major.  Bw: N x K bf16 row-major (torch Linear weight).
// tile 128x128, BK=32, 4 waves (2x2), each wave 64x64 via 4x4 MFMA 16x16x32.
#define GLD 40  // padded LDS stride (32 + 8), keeps 16B alignment, ~2-way banks

__global__ __launch_bounds__(256) void gemm_xwt(
    const float* __restrict__ A, const unsigned short* __restrict__ Bw,
    int M, int N, int K,
    unsigned short* __restrict__ ws_bhtd,  // bf16 (b,h,t,64) or null
    float* __restrict__ out_bhtd,          // fp32 (b,h,t,64) or null
    float* __restrict__ out_rm)            // fp32 row-major or null
{
  __shared__ short As[128 * GLD];
  __shared__ short Bs[128 * GLD];

  const int tid  = threadIdx.x;
  const int lane = tid & 63;
  const int w    = tid >> 6;
  const int wm = w >> 1, wn = w & 1;
  const int row0 = blockIdx.y * 128;
  const int col0 = blockIdx.x * 128;

  f32x4 acc[4][4];
#pragma unroll
  for (int m = 0; m < 4; ++m)
#pragma unroll
    for (int n = 0; n < 4; ++n) acc[m][n] = f32x4{0.f, 0.f, 0.f, 0.f};

  const int srow = tid >> 1;
  const int scb  = (tid & 1) * 16;
  const int lr = lane & 15;
  const int lk = (lane >> 4) * 8;

  for (int k0 = 0; k0 < K; k0 += 32) {
    __syncthreads();
    {  // stage A with fused fp32->bf16 cast
      const float* src = A + (size_t)(row0 + srow) * K + k0 + scb;
      float4 f0 = *reinterpret_cast<const float4*>(src + 0);
      float4 f1 = *reinterpret_cast<const float4*>(src + 4);
      float4 f2 = *reinterpret_cast<const float4*>(src + 8);
      float4 f3 = *reinterpret_cast<const float4*>(src + 12);
      s16x8 lo, hi;
      lo[0] = (short)f2bf(f0.x); lo[1] = (short)f2bf(f0.y);
      lo[2] = (short)f2bf(f0.z); lo[3] = (short)f2bf(f0.w);
      lo[4] = (short)f2bf(f1.x); lo[5] = (short)f2bf(f1.y);
      lo[6] = (short)f2bf(f1.z); lo[7] = (short)f2bf(f1.w);
      hi[0] = (short)f2bf(f2.x); hi[1] = (short)f2bf(f2.y);
      hi[2] = (short)f2bf(f2.z); hi[3] = (short)f2bf(f2.w);
      hi[4] = (short)f2bf(f3.x); hi[5] = (short)f2bf(f3.y);
      hi[6] = (short)f2bf(f3.z); hi[7] = (short)f2bf(f3.w);
      *reinterpret_cast<s16x8*>(&As[srow * GLD + scb + 0]) = lo;
      *reinterpret_cast<s16x8*>(&As[srow * GLD + scb + 8]) = hi;
    }
    {  // stage B (already bf16)
      const unsigned short* src = Bw + (size_t)(col0 + srow) * K + k0 + scb;
      *reinterpret_cast<s16x8*>(&Bs[srow * GLD + scb + 0]) =
          *reinterpret_cast<const s16x8*>(src + 0);
      *reinterpret_cast<s16x8*>(&Bs[srow * GLD + scb + 8]) =
          *reinterpret_cast<const s16x8*>(src + 8);
    }
    __syncthreads();

    s16x8 af[4], bf[4];
#pragma unroll
    for (int m = 0; m < 4; ++m)
      af[m] = *reinterpret_cast<const s16x8*>(&As[(wm * 64 + m * 16 + lr) * GLD + lk]);
#pragma unroll
    for (int n = 0; n < 4; ++n)
      bf[n] = *reinterpret_cast<const s16x8*>(&Bs[(wn * 64 + n * 16 + lr) * GLD + lk]);
#pragma unroll
    for (int m = 0; m < 4; ++m)
#pragma unroll
      for (int n = 0; n < 4; ++n)
        acc[m][n] = __builtin_amdgcn_mfma_f32_16x16x32_bf16(af[m], bf[n], acc[m][n], 0, 0, 0);
  }

  const int er = (lane >> 4) * 4;
  const int ec = lane & 15;
#pragma unroll
  for (int m = 0; m < 4; ++m) {
#pragma unroll
    for (int n = 0; n < 4; ++n) {
#pragma unroll
      for (int j = 0; j < 4; ++j) {
        int gm = row0 + wm * 64 + m * 16 + er + j;
        int gn = col0 + wn * 64 + n * 16 + ec;
        float v = acc[m][n][j];
        if (out_rm) out_rm[(size_t)gm * N + gn] = v;
        if (ws_bhtd) {
          int idx = (((gm >> 11) * 16 + (gn >> 6)) * 2048 + (gm & 2047)) * 64 + (gn & 63);
          ws_bhtd[idx] = f2bf(v);
          if (out_bhtd) out_bhtd[idx] = v;
        }
      }
    }
  }
}

// ---------------------------------------------------------------- fused causal attention
// grid (iblk=32, bh=32), 256 thr = 4 waves x 16 rows. Two passes over j-tiles:
// pass A: online row max + sumexp (registers only). pass B: recompute scores,
// write normalized att (fp32, zeros where masked), accumulate PV.
#define ALD 72  // 64 + 8 pad

__global__ __launch_bounds__(256) void attn_kernel(
    const unsigned short* __restrict__ qw, const unsigned short* __restrict__ kw,
    const unsigned short* __restrict__ vw, float* __restrict__ att_out,
    float* __restrict__ y_ws) {
  __shared__ short Kt[64 * ALD];
  __shared__ short Vt[64 * ALD];
  __shared__ short Pl[64 * ALD];  // 4 waves x 16 rows

  const int tid  = threadIdx.x;
  const int lane = tid & 63;
  const int w    = tid >> 6;
  const int bh   = blockIdx.y;
  const int iblk = blockIdx.x;
  const float scale = 0.03125f;  // 1/sqrt(1024)

  const int lr = lane & 15;
  const int lk = (lane >> 4) * 8;
  const int er = (lane >> 4) * 4;
  const int rbase = iblk * 64 + w * 16 + er;

  s16x8 aq[2];
  {
    const unsigned short* qb = qw + ((size_t)bh * 2048 + iblk * 64 + w * 16 + lr) * 64;
    aq[0] = *reinterpret_cast<const s16x8*>(qb + 0 + lk);
    aq[1] = *reinterpret_cast<const s16x8*>(qb + 32 + lk);
  }

  const int srow = tid >> 2;
  const int scb  = (tid & 3) * 16;

  float mrow[4], lrow[4];
#pragma unroll
  for (int j = 0; j < 4; ++j) { mrow[j] = -1e30f; lrow[j] = 0.f; }

  // ---- pass A: statistics
  for (int jt = 0; jt <= iblk; ++jt) {
    __syncthreads();
    {
      const unsigned short* src = kw + ((size_t)bh * 2048 + jt * 64 + srow) * 64 + scb;
      *reinterpret_cast<s16x8*>(&Kt[srow * ALD + scb + 0]) =
          *reinterpret_cast<const s16x8*>(src + 0);
      *reinterpret_cast<s16x8*>(&Kt[srow * ALD + scb + 8]) =
          *reinterpret_cast<const s16x8*>(src + 8);
    }
    __syncthreads();

    f32x4 s[4];
#pragma unroll
    for (int n = 0; n < 4; ++n) {
      s[n] = f32x4{0.f, 0.f, 0.f, 0.f};
#pragma unroll
      for (int ks = 0; ks < 2; ++ks) {
        s16x8 b = *reinterpret_cast<const s16x8*>(&Kt[(n * 16 + lr) * ALD + ks * 32 + lk]);
        s[n] = __builtin_amdgcn_mfma_f32_16x16x32_bf16(aq[ks], b, s[n], 0, 0, 0);
      }
    }
    float tmax[4] = {-1e30f, -1e30f, -1e30f, -1e30f};
#pragma unroll
    for (int n = 0; n < 4; ++n) {
      int c = jt * 64 + n * 16 + lr;
#pragma unroll
      for (int j = 0; j < 4; ++j) {
        float sv = s[n][j] * scale;
        if (c > rbase + j) sv = -1e30f;
        s[n][j] = sv;
        tmax[j] = fmaxf(tmax[j], sv);
      }
    }
#pragma unroll
    for (int j = 0; j < 4; ++j) {
#pragma unroll
      for (int msk = 1; msk < 16; msk <<= 1)
        tmax[j] = fmaxf(tmax[j], __shfl_xor(tmax[j], msk));
      float mn = fmaxf(mrow[j], tmax[j]);
      float sum = 0.f;
#pragma unroll
      for (int n = 0; n < 4; ++n) sum += __expf(s[n][j] - mn);
#pragma unroll
      for (int msk = 1; msk < 16; msk <<= 1) sum += __shfl_xor(sum, msk);
      lrow[j] = lrow[j] * __expf(mrow[j] - mn) + sum;
      mrow[j] = mn;
    }
  }

  float rl[4];
#pragma unroll
  for (int j = 0; j < 4; ++j) rl[j] = 1.0f / lrow[j];

  f32x4 yacc[4];
#pragma unroll
  for (int n = 0; n < 4; ++n) yacc[n] = f32x4{0.f, 0.f, 0.f, 0.f};

  // ---- pass B: write att + PV
  for (int jt = 0; jt <= iblk; ++jt) {
    __syncthreads();
    {
      const unsigned short* src = kw + ((size_t)bh * 2048 + jt * 64 + srow) * 64 + scb;
      *reinterpret_cast<s16x8*>(&Kt[srow * ALD + scb + 0]) =
          *reinterpret_cast<const s16x8*>(src + 0);
      *reinterpret_cast<s16x8*>(&Kt[srow * ALD + scb + 8]) =
          *reinterpret_cast<const s16x8*>(src + 8);
      const unsigned short* vs = vw + ((size_t)bh * 2048 + jt * 64 + srow) * 64 + scb;
      s16x8 v0 = *reinterpret_cast<const s16x8*>(vs + 0);
      s16x8 v1 = *reinterpret_cast<const s16x8*>(vs + 8);
#pragma unroll
      for (int e = 0; e < 8; ++e) Vt[(scb + e) * ALD + srow] = v0[e];
#pragma unroll
      for (int e = 0; e < 8; ++e) Vt[(scb + 8 + e) * ALD + srow] = v1[e];
    }
    __syncthreads();

    f32x4 s[4];
#pragma unroll
    for (int n = 0; n < 4; ++n) {
      s[n] = f32x4{0.f, 0.f, 0.f, 0.f};
#pragma unroll
      for (int ks = 0; ks < 2; ++ks) {
        s16x8 b = *reinterpret_cast<const s16x8*>(&Kt[(n * 16 + lr) * ALD + ks * 32 + lk]);
        s[n] = __builtin_amdgcn_mfma_f32_16x16x32_bf16(aq[ks], b, s[n], 0, 0, 0);
      }
    }
#pragma unroll
    for (int n = 0; n < 4; ++n) {
      int c = jt * 64 + n * 16 + lr;
#pragma unroll
      for (int j = 0; j < 4; ++j) {
        float sv = s[n][j] * scale;
        if (c > rbase + j) sv = -1e30f;
        float p = __expf(sv - mrow[j]) * rl[j];
        att_out[((size_t)bh * 2048 + rbase + j) * 2048 + c] = p;
        Pl[(w * 16 + er + j) * ALD + n * 16 + lr] = (short)f2bf(p);
      }
    }
    // PV: P (wave-private LDS) x Vt
#pragma unroll
    for (int ks = 0; ks < 2; ++ks) {
      s16x8 ap = *reinterpret_cast<const s16x8*>(&Pl[(w * 16 + lr) * ALD + ks * 32 + lk]);
#pragma unroll
      for (int n = 0; n < 4; ++n) {
        s16x8 bv = *reinterpret_cast<const s16x8*>(&Vt[(n * 16 + lr) * ALD + ks * 32 + lk]);
        yacc[n] = __builtin_amdgcn_mfma_f32_16x16x32_bf16(ap, bv, yacc[n], 0, 0, 0);
      }
    }
  }

  // write y (b, t, dim) fp32 workspace for final projection
  const int b = bh >> 4, h = bh & 15;
#pragma unroll
  for (int n = 0; n < 4; ++n)
#pragma unroll
    for (int j = 0; j < 4; ++j)
      y_ws[((size_t)b * 2048 + rbase + j) * 1024 + h * 64 + n * 16 + lr] = yacc[n][j];

  // zero-fill strictly-above-diagonal j-tiles
  int c0 = (iblk + 1) * 64;
  if (c0 < 2048) {
    int nv = (2048 - c0) >> 2;
    for (int r = 0; r < 64; ++r) {
      float4* dst = reinterpret_cast<float4*>(att_out + ((size_t)bh * 2048 + iblk * 64 + r) * 2048 + c0);
      for (int i = tid; i < nv; i += 256) dst[i] = make_float4(0.f, 0.f, 0.f, 0.f);
    }
  }
}

// ---------------------------------------------------------------- launch
extern "C" void kernel_launch(void* const* d_in, const int* in_sizes, int n_in,
                              void* d_out, int out_size, void* d_ws, size_t ws_size,
                              hipStream_t stream) {
  (void)in_sizes; (void)n_in; (void)out_size; (void)ws_size;
  const float* Q  = (const float*)d_in[0];
  const float* K  = (const float*)d_in[1];
  const float* V  = (const float*)d_in[2];
  const float* Wq = (const float*)d_in[3];
  const float* Wk = (const float*)d_in[4];
  const float* Wv = (const float*)d_in[5];
  const float* Wp = (const float*)d_in[6];
  float* out = (float*)d_out;

  char* ws = (char*)d_ws;
  unsigned short* qws = (unsigned short*)(ws + 0);
  unsigned short* kws = (unsigned short*)(ws + 8388608);
  unsigned short* vws = (unsigned short*)(ws + 16777216);
  unsigned short* wqb = (unsigned short*)(ws + 25165824);
  unsigned short* wkb = (unsigned short*)(ws + 27262976);
  unsigned short* wvb = (unsigned short*)(ws + 29360128);
  unsigned short* wpb = (unsigned short*)(ws + 31457280);
  float*          yws = (float*)(ws + 33554432);  // 16 MB, total 48 MB

  float* y_out   = out;
  float* att_out = out + 4194304;
  float* k_out   = out + 138412032;
  float* v_out   = out + 142606336;

  cast_w<<<dim3(1024), dim3(256), 0, stream>>>(Wq, wqb, 1048576);
  cast_w<<<dim3(1024), dim3(256), 0, stream>>>(Wk, wkb, 1048576);
  cast_w<<<dim3(1024), dim3(256), 0, stream>>>(Wv, wvb, 1048576);
  cast_w<<<dim3(1024), dim3(256), 0, stream>>>(Wp, wpb, 1048576);

  dim3 ggrid(8, 32), gblk(256);
  gemm_xwt<<<ggrid, gblk, 0, stream>>>(Q, wqb, 4096, 1024, 1024, qws, nullptr, nullptr);
  gemm_xwt<<<ggrid, gblk, 0, stream>>>(K, wkb, 4096, 1024, 1024, kws, k_out, nullptr);
  gemm_xwt<<<ggrid, gblk, 0, stream>>>(V, wvb, 4096, 1024, 1024, vws, v_out, nullptr);

  attn_kernel<<<dim3(32, 32), dim3(256), 0, stream>>>(qws, kws, vws, att_out, yws);

  gemm_xwt<<<ggrid, gblk, 0, stream>>>(yws, wpb, 4096, 1024, 1024, nullptr, nullptr, y_out);
}

// Round 2
// 312.963 us; speedup vs baseline: 1.4080x; 1.4080x over previous
//
#include <hip/hip_runtime.h>

typedef __attribute__((ext_vector_type(8))) short s16x8;
typedef __attribute__((ext_vector_type(4))) float f32x4;

static __device__ __forceinline__ unsigned short f2bf(float f) {
  union { float f; unsigned int u; } v; v.f = f;
  unsigned int u = v.u;
  u += 0x7fffu + ((u >> 16) & 1u);
  return (unsigned short)(u >> 16);
}
static __device__ __forceinline__ float bf2f(unsigned short u) {
  union { unsigned int u; float f; } v; v.u = ((unsigned int)u) << 16;
  return v.f;
}
static __device__ __forceinline__ void gload16(const void* g, void* l) {
  __builtin_amdgcn_global_load_lds((const __attribute__((address_space(1))) unsigned int*)g,
                                   (__attribute__((address_space(3))) unsigned int*)l, 16, 0, 0);
}

// ---------------------------------------------------------------- casts (fp32 -> bf16), 8 elem/thread
__global__ __launch_bounds__(256) void cast4_bf16(
    const float* __restrict__ i0, const float* __restrict__ i1,
    const float* __restrict__ i2, const float* __restrict__ i3,
    unsigned short* __restrict__ o0, unsigned short* __restrict__ o1,
    unsigned short* __restrict__ o2, unsigned short* __restrict__ o3) {
  const int z = blockIdx.z;
  const float* in = z == 0 ? i0 : z == 1 ? i1 : z == 2 ? i2 : i3;
  unsigned short* out = z == 0 ? o0 : z == 1 ? o1 : z == 2 ? o2 : o3;
  int i = (blockIdx.x * 256 + threadIdx.x) * 8;
  float4 a = *reinterpret_cast<const float4*>(in + i);
  float4 b = *reinterpret_cast<const float4*>(in + i + 4);
  s16x8 o;
  o[0] = (short)f2bf(a.x); o[1] = (short)f2bf(a.y);
  o[2] = (short)f2bf(a.z); o[3] = (short)f2bf(a.w);
  o[4] = (short)f2bf(b.x); o[5] = (short)f2bf(b.y);
  o[6] = (short)f2bf(b.z); o[7] = (short)f2bf(b.w);
  *reinterpret_cast<s16x8*>(out + i) = o;
}

// ---------------------------------------------------------------- GEMM C = A @ W^T (bf16 in, K=1024)
// tile 128(M) x 64(N), BK=64, 4 waves (2m x 2n), wave = 64x32 via acc[4][2].
// LDS linear [rows][128B] with XOR swizzle byte ^= (row&7)<<4 (pre-swizzled global src).
__global__ __launch_bounds__(256) void gemm_bf16(
    const unsigned short* __restrict__ A0, const unsigned short* __restrict__ A1,
    const unsigned short* __restrict__ A2,
    const unsigned short* __restrict__ W0, const unsigned short* __restrict__ W1,
    const unsigned short* __restrict__ W2,
    unsigned short* __restrict__ O0, unsigned short* __restrict__ O1,
    unsigned short* __restrict__ O2,
    unsigned short* __restrict__ Ot2,  // (b,h,d,t) bf16, z==2 only
    float* __restrict__ Orm)           // fp32 row-major (final proj)
{
  __shared__ short As[128 * 64];
  __shared__ short Bs[64 * 64];

  const int z = blockIdx.z;
  const unsigned short* A = z == 0 ? A0 : z == 1 ? A1 : A2;
  const unsigned short* W = z == 0 ? W0 : z == 1 ? W1 : W2;
  unsigned short* On = z == 0 ? O0 : z == 1 ? O1 : O2;
  unsigned short* Ot = (z == 2) ? Ot2 : nullptr;

  const int tid = threadIdx.x;
  const int lane = tid & 63;
  const int w = tid >> 6;
  const int wm = w >> 1, wn = w & 1;
  const int row0 = blockIdx.y * 128;
  const int col0 = blockIdx.x * 64;

  f32x4 acc[4][2];
#pragma unroll
  for (int m = 0; m < 4; ++m)
#pragma unroll
    for (int n = 0; n < 2; ++n) acc[m][n] = f32x4{0.f, 0.f, 0.f, 0.f};

  // staging: thread covers 16 B; flat = p*4096 + tid*16 bytes; row = flat>>7, col byte = flat&127
  const int srow = tid >> 3;                 // within 32-row pass group
  const int scb = (tid & 7) * 16;            // col byte (pre-swizzle)
  const int swcb = scb ^ ((srow & 7) << 4);  // swizzled source col byte
  const unsigned short* aSrc = A + (size_t)(row0 + srow) * 1024 + (swcb >> 1);
  const unsigned short* bSrc = W + (size_t)(col0 + srow) * 1024 + (swcb >> 1);
  char* ldsA = (char*)As + w * 1024;
  char* ldsB = (char*)Bs + w * 1024;

  const int lr = lane & 15;
  const int lk2 = ((lane >> 4) * 8) * 2;  // k byte within 64B slice

  for (int k0 = 0; k0 < 1024; k0 += 64) {
    __syncthreads();
#pragma unroll
    for (int p = 0; p < 4; ++p) gload16(aSrc + k0 + p * 32 * 1024, ldsA + p * 4096);
#pragma unroll
    for (int p = 0; p < 2; ++p) gload16(bSrc + k0 + p * 32 * 1024, ldsB + p * 4096);
    __syncthreads();

    s16x8 af[2][4], bf[2][2];
#pragma unroll
    for (int ks = 0; ks < 2; ++ks) {
#pragma unroll
      for (int m = 0; m < 4; ++m) {
        int r = wm * 64 + m * 16 + lr;
        int cb = (ks * 64 + lk2) ^ ((r & 7) << 4);
        af[ks][m] = *reinterpret_cast<const s16x8*>((const char*)As + r * 128 + cb);
      }
#pragma unroll
      for (int n = 0; n < 2; ++n) {
        int r = wn * 32 + n * 16 + lr;
        int cb = (ks * 64 + lk2) ^ ((r & 7) << 4);
        bf[ks][n] = *reinterpret_cast<const s16x8*>((const char*)Bs + r * 128 + cb);
      }
    }
#pragma unroll
    for (int ks = 0; ks < 2; ++ks)
#pragma unroll
      for (int m = 0; m < 4; ++m)
#pragma unroll
        for (int n = 0; n < 2; ++n)
          acc[m][n] = __builtin_amdgcn_mfma_f32_16x16x32_bf16(af[ks][m], bf[ks][n], acc[m][n], 0, 0, 0);
  }

  const int er = (lane >> 4) * 4;
  const int ec = lane & 15;

  if (Orm) {  // final projection: fp32 row-major scalar stores
#pragma unroll
    for (int m = 0; m < 4; ++m)
#pragma unroll
      for (int n = 0; n < 2; ++n)
#pragma unroll
        for (int j = 0; j < 4; ++j) {
          int gm = row0 + wm * 64 + m * 16 + er + j;
          int gn = col0 + wn * 32 + n * 16 + ec;
          Orm[(size_t)gm * 1024 + gn] = acc[m][n][j];
        }
  }

  if (Ot) {  // V transposed (b,h,d,t): ushort4 per (m,n)
    const int b = row0 >> 11, h = blockIdx.x;
    const int tl = (row0 & 2047) + wm * 64 + er;
#pragma unroll
    for (int m = 0; m < 4; ++m)
#pragma unroll
      for (int n = 0; n < 2; ++n) {
        int d = wn * 32 + n * 16 + ec;
        ushort4 u;
        u.x = f2bf(acc[m][n][0]); u.y = f2bf(acc[m][n][1]);
        u.z = f2bf(acc[m][n][2]); u.w = f2bf(acc[m][n][3]);
        *reinterpret_cast<ushort4*>(Ot2 + ((size_t)(b * 16 + h) * 64 + d) * 2048 + tl + m * 16) = u;
      }
  }

  if (On) {  // (b,h,t,64) bf16 via LDS-staged vector stores (swizzled C tile in As)
    __syncthreads();
#pragma unroll
    for (int m = 0; m < 4; ++m)
#pragma unroll
      for (int n = 0; n < 2; ++n)
#pragma unroll
        for (int j = 0; j < 4; ++j) {
          int r = wm * 64 + m * 16 + er + j;
          int cb = ((wn * 32 + n * 16 + ec) * 2) ^ ((r & 7) << 4);
          *reinterpret_cast<short*>((char*)As + r * 128 + cb) = (short)f2bf(acc[m][n][j]);
        }
    __syncthreads();
    const int r = tid >> 1;
    const int sgb = (tid & 1) * 64;  // byte offset of 64B half
    int gt = row0 + r;
    int b = gt >> 11, t = gt & 2047, h = blockIdx.x;
    unsigned short* dst = On + ((size_t)(b * 16 + h) * 2048 + t) * 64 + (sgb >> 1);
#pragma unroll
    for (int i = 0; i < 4; ++i) {
      int cb = (sgb + i * 16) ^ ((r & 7) << 4);
      *reinterpret_cast<s16x8*>(dst + i * 8) =
          *reinterpret_cast<const s16x8*>((const char*)As + r * 128 + cb);
    }
  }
}

// ---------------------------------------------------------------- fused causal attention
#define ALD 72

__global__ __launch_bounds__(256) void attn_kernel(
    const unsigned short* __restrict__ qw, const unsigned short* __restrict__ kw,
    const unsigned short* __restrict__ vt, float* __restrict__ att_out,
    float* __restrict__ k_out, float* __restrict__ v_out,
    unsigned short* __restrict__ yb) {
  __shared__ short Kt[64 * ALD];
  __shared__ short Vt[64 * ALD];
  __shared__ short Pl[64 * ALD];

  const int tid = threadIdx.x;
  const int lane = tid & 63;
  const int w = tid >> 6;
  const int bh = blockIdx.y;
  const int iblk = blockIdx.x;
  const float scale = 0.03125f;

  const int lr = lane & 15;
  const int lk = (lane >> 4) * 8;
  const int er = (lane >> 4) * 4;
  const int rbase = iblk * 64 + w * 16 + er;

  s16x8 aq[2];
  {
    const unsigned short* qb = qw + ((size_t)bh * 2048 + iblk * 64 + w * 16 + lr) * 64;
    aq[0] = *reinterpret_cast<const s16x8*>(qb + 0 + lk);
    aq[1] = *reinterpret_cast<const s16x8*>(qb + 32 + lk);
  }

  const int srow = tid >> 2;
  const int scb = (tid & 3) * 16;

  float mrow[4], lrow[4];
#pragma unroll
  for (int j = 0; j < 4; ++j) { mrow[j] = -1e30f; lrow[j] = 0.f; }

  // ---- pass A: per-lane online stats (no per-tile cross-lane reduction)
  for (int jt = 0; jt <= iblk; ++jt) {
    __syncthreads();
    {
      const unsigned short* src = kw + ((size_t)bh * 2048 + jt * 64 + srow) * 64 + scb;
      *reinterpret_cast<s16x8*>(&Kt[srow * ALD + scb + 0]) = *reinterpret_cast<const s16x8*>(src + 0);
      *reinterpret_cast<s16x8*>(&Kt[srow * ALD + scb + 8]) = *reinterpret_cast<const s16x8*>(src + 8);
    }
    __syncthreads();

    if (jt == iblk) {  // emit fp32 K tile (upcast) once per (bh, tile)
      const short* src = &Kt[srow * ALD + scb];
      float* dst = k_out + ((size_t)bh * 2048 + iblk * 64 + srow) * 64 + scb;
#pragma unroll
      for (int q = 0; q < 4; ++q) {
        float4 f;
        f.x = bf2f((unsigned short)src[q * 4 + 0]);
        f.y = bf2f((unsigned short)src[q * 4 + 1]);
        f.z = bf2f((unsigned short)src[q * 4 + 2]);
        f.w = bf2f((unsigned short)src[q * 4 + 3]);
        reinterpret_cast<float4*>(dst)[q] = f;
      }
    }

    f32x4 s[4];
#pragma unroll
    for (int n = 0; n < 4; ++n) {
      s[n] = f32x4{0.f, 0.f, 0.f, 0.f};
#pragma unroll
      for (int ks = 0; ks < 2; ++ks) {
        s16x8 b = *reinterpret_cast<const s16x8*>(&Kt[(n * 16 + lr) * ALD + ks * 32 + lk]);
        s[n] = __builtin_amdgcn_mfma_f32_16x16x32_bf16(aq[ks], b, s[n], 0, 0, 0);
      }
    }
#pragma unroll
    for (int n = 0; n < 4; ++n) {
      int c = jt * 64 + n * 16 + lr;
#pragma unroll
      for (int j = 0; j < 4; ++j) {
        float sv = s[n][j] * scale;
        if (c > rbase + j) sv = -1e30f;
        s[n][j] = sv;
      }
    }
#pragma unroll
    for (int j = 0; j < 4; ++j) {
      float tm = fmaxf(fmaxf(s[0][j], s[1][j]), fmaxf(s[2][j], s[3][j]));
      float nm = fmaxf(mrow[j], tm);
      float sum = 0.f;
#pragma unroll
      for (int n = 0; n < 4; ++n)
        sum += (s[n][j] > -1e29f) ? __expf(s[n][j] - nm) : 0.f;
      lrow[j] = lrow[j] * __expf(mrow[j] - nm) + sum;
      mrow[j] = nm;
    }
  }

  // merge (m,l) across the 16 lanes of each er-group
#pragma unroll
  for (int j = 0; j < 4; ++j) {
#pragma unroll
    for (int msk = 1; msk < 16; msk <<= 1) {
      float mo = __shfl_xor(mrow[j], msk);
      float lo = __shfl_xor(lrow[j], msk);
      float nm = fmaxf(mrow[j], mo);
      lrow[j] = lrow[j] * __expf(mrow[j] - nm) + lo * __expf(mo - nm);
      mrow[j] = nm;
    }
  }
  float rl[4];
#pragma unroll
  for (int j = 0; j < 4; ++j) rl[j] = 1.0f / lrow[j];

  f32x4 yacc[4];
#pragma unroll
  for (int n = 0; n < 4; ++n) yacc[n] = f32x4{0.f, 0.f, 0.f, 0.f};

  // ---- pass B: write att + PV
  for (int jt = 0; jt <= iblk; ++jt) {
    __syncthreads();
    {
      const unsigned short* src = kw + ((size_t)bh * 2048 + jt * 64 + srow) * 64 + scb;
      *reinterpret_cast<s16x8*>(&Kt[srow * ALD + scb + 0]) = *reinterpret_cast<const s16x8*>(src + 0);
      *reinterpret_cast<s16x8*>(&Kt[srow * ALD + scb + 8]) = *reinterpret_cast<const s16x8*>(src + 8);
      const unsigned short* vs = vt + ((size_t)bh * 64 + srow) * 2048 + jt * 64 + scb;
      *reinterpret_cast<s16x8*>(&Vt[srow * ALD + scb + 0]) = *reinterpret_cast<const s16x8*>(vs + 0);
      *reinterpret_cast<s16x8*>(&Vt[srow * ALD + scb + 8]) = *reinterpret_cast<const s16x8*>(vs + 8);
    }
    __syncthreads();

    if (jt == iblk) {  // emit fp32 V tile (transposed back to (t,d)) once per (bh, tile)
      const int jr = tid >> 2, d0 = (tid & 3) * 16;
      float* dst = v_out + ((size_t)bh * 2048 + iblk * 64 + jr) * 64 + d0;
#pragma unroll
      for (int q = 0; q < 4; ++q) {
        float4 f;
        f.x = bf2f((unsigned short)Vt[(d0 + q * 4 + 0) * ALD + jr]);
        f.y = bf2f((unsigned short)Vt[(d0 + q * 4 + 1) * ALD + jr]);
        f.z = bf2f((unsigned short)Vt[(d0 + q * 4 + 2) * ALD + jr]);
        f.w = bf2f((unsigned short)Vt[(d0 + q * 4 + 3) * ALD + jr]);
        reinterpret_cast<float4*>(dst)[q] = f;
      }
    }

    f32x4 s[4];
#pragma unroll
    for (int n = 0; n < 4; ++n) {
      s[n] = f32x4{0.f, 0.f, 0.f, 0.f};
#pragma unroll
      for (int ks = 0; ks < 2; ++ks) {
        s16x8 b = *reinterpret_cast<const s16x8*>(&Kt[(n * 16 + lr) * ALD + ks * 32 + lk]);
        s[n] = __builtin_amdgcn_mfma_f32_16x16x32_bf16(aq[ks], b, s[n], 0, 0, 0);
      }
    }
#pragma unroll
    for (int n = 0; n < 4; ++n) {
      int c = jt * 64 + n * 16 + lr;
#pragma unroll
      for (int j = 0; j < 4; ++j) {
        float sv = s[n][j] * scale;
        if (c > rbase + j) sv = -1e30f;
        float p = __expf(sv - mrow[j]) * rl[j];
        att_out[((size_t)bh * 2048 + rbase + j) * 2048 + c] = p;
        Pl[(w * 16 + er + j) * ALD + n * 16 + lr] = (short)f2bf(p);
      }
    }
#pragma unroll
    for (int ks = 0; ks < 2; ++ks) {
      s16x8 ap = *reinterpret_cast<const s16x8*>(&Pl[(w * 16 + lr) * ALD + ks * 32 + lk]);
#pragma unroll
      for (int n = 0; n < 4; ++n) {
        s16x8 bv = *reinterpret_cast<const s16x8*>(&Vt[(n * 16 + lr) * ALD + ks * 32 + lk]);
        yacc[n] = __builtin_amdgcn_mfma_f32_16x16x32_bf16(ap, bv, yacc[n], 0, 0, 0);
      }
    }
  }

  // y -> bf16 (b,t,1024)
  const int b = bh >> 4, h = bh & 15;
#pragma unroll
  for (int n = 0; n < 4; ++n)
#pragma unroll
    for (int j = 0; j < 4; ++j)
      yb[((size_t)b * 2048 + rbase + j) * 1024 + h * 64 + n * 16 + lr] = f2bf(yacc[n][j]);

  // zero-fill above-diagonal tail
  int c0 = (iblk + 1) * 64;
  if (c0 < 2048) {
    int nv = (2048 - c0) >> 2;
    const float4 z4 = make_float4(0.f, 0.f, 0.f, 0.f);
    for (int rr = 0; rr < 64; rr += 4) {
      int r = rr + w;
      float4* dst = reinterpret_cast<float4*>(att_out + ((size_t)bh * 2048 + iblk * 64 + r) * 2048 + c0);
      for (int i = lane; i < nv; i += 64) dst[i] = z4;
    }
  }
}

// ---------------------------------------------------------------- launch
extern "C" void kernel_launch(void* const* d_in, const int* in_sizes, int n_in,
                              void* d_out, int out_size, void* d_ws, size_t ws_size,
                              hipStream_t stream) {
  (void)in_sizes; (void)n_in; (void)out_size; (void)ws_size;
  const float* Q = (const float*)d_in[0];
  const float* K = (const float*)d_in[1];
  const float* V = (const float*)d_in[2];
  const float* Wq = (const float*)d_in[3];
  const float* Wk = (const float*)d_in[4];
  const float* Wv = (const float*)d_in[5];
  const float* Wp = (const float*)d_in[6];
  float* out = (float*)d_out;

  char* ws = (char*)d_ws;
  const size_t MB = 1024 * 1024;
  unsigned short* qb = (unsigned short*)(ws + 0 * MB);
  unsigned short* kb = (unsigned short*)(ws + 8 * MB);
  unsigned short* vb = (unsigned short*)(ws + 16 * MB);
  unsigned short* wqb = (unsigned short*)(ws + 24 * MB);
  unsigned short* wkb = (unsigned short*)(ws + 26 * MB);
  unsigned short* wvb = (unsigned short*)(ws + 28 * MB);
  unsigned short* wpb = (unsigned short*)(ws + 30 * MB);
  unsigned short* qws = (unsigned short*)(ws + 32 * MB);
  unsigned short* kws = (unsigned short*)(ws + 40 * MB);
  unsigned short* vwt = (unsigned short*)(ws + 48 * MB);
  unsigned short* yb = (unsigned short*)(ws + 0 * MB);  // reuses qb (dead after QKV GEMM)

  float* y_out = out;
  float* att_out = out + 4194304;
  float* k_out = out + 138412032;
  float* v_out = out + 142606336;

  cast4_bf16<<<dim3(2048, 1, 3), 256, 0, stream>>>(Q, K, V, nullptr, qb, kb, vb, nullptr);
  cast4_bf16<<<dim3(512, 1, 4), 256, 0, stream>>>(Wq, Wk, Wv, Wp, wqb, wkb, wvb, wpb);

  gemm_bf16<<<dim3(16, 32, 3), 256, 0, stream>>>(qb, kb, vb, wqb, wkb, wvb,
                                                 qws, kws, nullptr, vwt, nullptr);

  attn_kernel<<<dim3(32, 32), 256, 0, stream>>>(qws, kws, vwt, att_out, k_out, v_out, yb);

  gemm_bf16<<<dim3(16, 32, 1), 256, 0, stream>>>(yb, nullptr, nullptr, wpb, nullptr, nullptr,
                                                 nullptr, nullptr, nullptr, nullptr, y_out);
}